// Round 7
// baseline (2800.497 us; speedup 1.0000x reference)
//
#include <hip/hip_runtime.h>
#include <hip/hip_bf16.h>

typedef __attribute__((ext_vector_type(8))) short short8;
typedef __attribute__((ext_vector_type(4))) float float4_;

typedef const __attribute__((address_space(1))) void* gas_t;
typedef __attribute__((address_space(3))) void* las_t;

// Async global->LDS, 16 B/lane. LDS dest is wave-uniform base + lane*16.
__device__ __forceinline__ void gl_lds16(const void* g, void* l) {
  __builtin_amdgcn_global_load_lds((gas_t)g, (las_t)l, 16, 0, 0);
}

__device__ __forceinline__ short f2b(float f) {
  union { __hip_bfloat16 h; short s; } u;
  u.h = __float2bfloat16(f);
  return u.s;
}
__device__ __forceinline__ short8 cvt8(float4_ lo, float4_ hi) {
  short8 r;
#pragma unroll
  for (int t = 0; t < 4; t++) { r[t] = f2b(lo[t]); r[t + 4] = f2b(hi[t]); }
  return r;
}

// Fused prep: [0,768) transpose Wqkv -> WqkvT (bf16, [3072][1024]);
// [768,1280) convert Wout -> bf16; [1280,...) convert x -> bf16 (if has_x).
__global__ __launch_bounds__(256) void prep(
    const float* __restrict__ Wqkv, short* __restrict__ WqkvT,
    const float* __restrict__ Wout, short* __restrict__ Woutb,
    const float* __restrict__ x, short* __restrict__ xb, int has_x)
{
  __shared__ __align__(16) short T[64 * 72];
  const int b   = blockIdx.x;
  const int tid = threadIdx.x;
  if (b < 768) {
    const int R = 1024, C = 3072;
    const int r0 = (b / 48) * 64;
    const int c0 = (b % 48) * 64;
    const int r  = tid >> 2;
    const int cp = (tid & 3) * 16;
#pragma unroll
    for (int g = 0; g < 4; g++) {
      float4_ v = *(const float4_*)&Wqkv[(long)(r0 + r) * C + c0 + cp + g * 4];
#pragma unroll
      for (int t = 0; t < 4; t++) T[(cp + g * 4 + t) * 72 + r] = f2b(v[t]);
    }
    __syncthreads();
    const int c  = tid >> 2;
    const int rp = (tid & 3) * 16;
    short8 w0 = *(const short8*)&T[c * 72 + rp];
    short8 w1 = *(const short8*)&T[c * 72 + rp + 8];
    *(short8*)&WqkvT[(long)(c0 + c) * R + r0 + rp] = w0;
    *(short8*)&WqkvT[(long)(c0 + c) * R + r0 + rp + 8] = w1;
  } else if (b < 1280) {
    const long i = ((long)(b - 768) * 256 + tid) * 8;
    float4_ lo = *(const float4_*)&Wout[i];
    float4_ hi = *(const float4_*)&Wout[i + 4];
    *(short8*)&Woutb[i] = cvt8(lo, hi);
  } else if (has_x) {
    const long i = ((long)(b - 1280) * 256 + tid) * 8;
    float4_ lo = *(const float4_*)&x[i];
    float4_ hi = *(const float4_*)&x[i + 4];
    *(short8*)&xb[i] = cvt8(lo, hi);
  }
}

// ============================================================================
// gemm_bt_p: C[M,N] = A[M,K] @ B[N,K]^T (+bias), A,B bf16. 128x128 tile,
// 4 waves (2x2 of 64x64), BK=32, DOUBLE-buffered LDS (2 x 16 KB), pipelined:
// tile t+1's global_load_lds issued BEFORE tile t's compute; ONE
// __syncthreads() per K-step (drains vmcnt for t+1's loads AFTER they had a
// full compute phase in flight; also fences LDS reads before t+2 overwrite).
// 64 B LDS rows: chunk-XOR swizzle  chunk ^= (row>>1)&3  -> 8 bank windows
// per 16-lane group = 2-way (free). Swizzle applied both-sides: pre-swizzled
// gl_lds SOURCE + swizzled ds_read address (rule #21).
// XCD-bijective block swizzle (grids used are %8==0).
// ============================================================================
__global__ __launch_bounds__(256) void gemm_bt_p(
    const short* __restrict__ A, int lda,
    const short* __restrict__ B,
    void* __restrict__ Cv, int ldc, int c_f32,
    int K, const float* __restrict__ bias)
{
  __shared__ __align__(16) short As[2][128 * 32];  // 16 KB (epilogue scratch too)
  __shared__ __align__(16) short Bs[2][128 * 32];  // 16 KB
  const int tid  = threadIdx.x;
  const int lane = tid & 63;
  const int w    = tid >> 6;
  const int quad = lane >> 4;
  const int l15  = lane & 15;
  const int wm   = (w >> 1) * 64;
  const int wn   = (w & 1) * 64;

  const int nx  = gridDim.x;
  const int nwg = nx * gridDim.y;
  int wid = blockIdx.y * nx + blockIdx.x;
  if ((nwg & 7) == 0) wid = (wid & 7) * (nwg >> 3) + (wid >> 3);
  const int m0 = (wid / nx) * 128;
  const int n0 = (wid % nx) * 128;

  float4_ acc[4][4] = {};

  // staging: 2 calls/operand; call g covers rows g*64 + (tid>>2).
  const int srow  = tid >> 2;                          // 0..63
  const int kswz  = (((tid & 3) ^ ((srow >> 1) & 3)) * 8);  // pre-swizzled src
  const int wbase = w * 512;                           // linear dest, lane*8
  // read-side swizzled chunk: (quad ^ ((l15>>1)&3)) * 8
  const int rsz   = ((l15 >> 1) & 3);

  const int nt = K >> 5;                               // 32-wide K-steps

  // prologue: stage tile 0 into buffer 0
  gl_lds16(&A[(long)(m0 + srow) * lda + kswz],      &As[0][wbase]);
  gl_lds16(&A[(long)(m0 + 64 + srow) * lda + kswz], &As[0][2048 + wbase]);
  gl_lds16(&B[(long)(n0 + srow) * K + kswz],        &Bs[0][wbase]);
  gl_lds16(&B[(long)(n0 + 64 + srow) * K + kswz],   &Bs[0][2048 + wbase]);
  __syncthreads();

  int cur = 0;
#pragma unroll 1
  for (int t = 0; t < nt; ++t) {
    if (t + 1 < nt) {
      const long k1 = (long)(t + 1) << 5;
      gl_lds16(&A[(long)(m0 + srow) * lda + k1 + kswz],      &As[cur ^ 1][wbase]);
      gl_lds16(&A[(long)(m0 + 64 + srow) * lda + k1 + kswz], &As[cur ^ 1][2048 + wbase]);
      gl_lds16(&B[(long)(n0 + srow) * K + k1 + kswz],        &Bs[cur ^ 1][wbase]);
      gl_lds16(&B[(long)(n0 + 64 + srow) * K + k1 + kswz],   &Bs[cur ^ 1][2048 + wbase]);
    }
    short8 a[4], b[4];
#pragma unroll
    for (int i = 0; i < 4; i++)
      a[i] = *(const short8*)&As[cur][(wm + i * 16 + l15) * 32 + ((quad ^ rsz) * 8)];
#pragma unroll
    for (int j = 0; j < 4; j++)
      b[j] = *(const short8*)&Bs[cur][(wn + j * 16 + l15) * 32 + ((quad ^ rsz) * 8)];
#pragma unroll
    for (int i = 0; i < 4; i++)
#pragma unroll
      for (int j = 0; j < 4; j++)
        acc[i][j] = __builtin_amdgcn_mfma_f32_16x16x32_bf16(a[i], b[j], acc[i][j], 0, 0, 0);
    __syncthreads();  // t+1 loads landed; all waves' reads of buf cur done
    cur ^= 1;
  }

  // Epilogue: per i-strip, transpose acc through LDS scratch (XOR-swizzled),
  // coalesced float4/short8 stores. (R4/R5-verified pattern.)
  float* scrf = (float*)As;      // [32][128] fp32 = 16 KB
  short* scrh = (short*)As;      // [32][128] bf16 =  8 KB
  const int gidx = w >> 1;
#pragma unroll 1
  for (int i = 0; i < 4; i++) {
    __syncthreads();
    if (c_f32) {
#pragma unroll
      for (int j = 0; j < 4; j++) {
        const int col = wn + j * 16 + l15;
        const float bv = bias ? bias[n0 + col] : 0.0f;
#pragma unroll
        for (int r = 0; r < 4; r++) {
          const int row = gidx * 16 + quad * 4 + r;
          scrf[row * 128 + (col ^ ((row & 7) << 4))] = acc[i][j][r] + bv;
        }
      }
    } else {
#pragma unroll
      for (int j = 0; j < 4; j++) {
        const int col = wn + j * 16 + l15;
#pragma unroll
        for (int r = 0; r < 4; r++) {
          const int row = gidx * 16 + quad * 4 + r;
          scrh[row * 128 + (col ^ ((row & 7) << 4))] = f2b(acc[i][j][r]);
        }
      }
    }
    __syncthreads();
    const int rs   = tid >> 3;          // 0..31
    const int colp = (tid & 7) * 16;    // 0..112
    const int cs   = colp ^ ((rs & 7) << 4);
    const long row_g = m0 + (rs >> 4) * 64 + i * 16 + (rs & 15);
    if (c_f32) {
      float* C = (float*)Cv;
#pragma unroll
      for (int q = 0; q < 4; q++)
        *(float4_*)&C[row_g * ldc + n0 + colp + q * 4] =
            *(const float4_*)&scrf[rs * 128 + cs + q * 4];
    } else {
      short* C = (short*)Cv;
      *(short8*)&C[row_g * ldc + n0 + colp]     = *(const short8*)&scrh[rs * 128 + cs];
      *(short8*)&C[row_g * ldc + n0 + colp + 8] = *(const short8*)&scrh[rs * 128 + cs + 8];
    }
  }
}

// C[M,N] = A[M,K] @ B[N,K]^T, A fp32 (reg-staged+converted) or bf16. 128x128
// tile, 4 waves, BK=64, chunk-XOR swizzle. (Verified R4/R5 code, unchanged —
// used for fp32-A tiers.)
__global__ __launch_bounds__(256) void gemm_bt(
    const void* __restrict__ Av, int lda, int a_f32,
    const short* __restrict__ B,
    void* __restrict__ Cv, int ldc, int c_f32,
    int K, const float* __restrict__ bias)
{
  __shared__ __align__(16) short As[128 * 64];
  __shared__ __align__(16) short Bs[128 * 64];
  const int tid  = threadIdx.x;
  const int lane = tid & 63;
  const int w    = tid >> 6;
  const int quad = lane >> 4;
  const int l15  = lane & 15;
  const int wm   = (w >> 1) * 64;
  const int wn   = (w & 1) * 64;

  const int nx  = gridDim.x;
  const int nwg = nx * gridDim.y;
  int wid = blockIdx.y * nx + blockIdx.x;
  if ((nwg & 7) == 0) wid = (wid & 7) * (nwg >> 3) + (wid >> 3);
  const int m0 = (wid / nx) * 128;
  const int n0 = (wid % nx) * 128;

  float4_ acc[4][4] = {};

  const int srow = tid >> 3;
  const int sk   = tid & 7;
  const int kswz = ((sk ^ (srow & 7)) * 8);
  const int wbase = w * 512;
  const int frow = tid >> 1;
  const int fh   = tid & 1;

  for (int k0 = 0; k0 < K; k0 += 64) {
    short8 fs[4];
    if (a_f32) {
      const float* Af = (const float*)Av;
#pragma unroll
      for (int g = 0; g < 2; g++) {
        float4_ v0 = *(const float4_*)&Af[(long)(m0 + frow) * lda + k0 + fh * 32 + g * 16];
        float4_ v1 = *(const float4_*)&Af[(long)(m0 + frow) * lda + k0 + fh * 32 + g * 16 + 4];
        float4_ v2 = *(const float4_*)&Af[(long)(m0 + frow) * lda + k0 + fh * 32 + g * 16 + 8];
        float4_ v3 = *(const float4_*)&Af[(long)(m0 + frow) * lda + k0 + fh * 32 + g * 16 + 12];
        fs[g * 2]     = cvt8(v0, v1);
        fs[g * 2 + 1] = cvt8(v2, v3);
      }
    }
    __syncthreads();
    if (a_f32) {
#pragma unroll
      for (int g = 0; g < 4; g++) {
        const int c_log = fh * 4 + g;
        *(short8*)&As[frow * 64 + ((c_log ^ (frow & 7)) * 8)] = fs[g];
      }
    } else {
      const short* Ab = (const short*)Av;
#pragma unroll
      for (int g = 0; g < 4; g++)
        gl_lds16(&Ab[(long)(m0 + g * 32 + srow) * lda + k0 + kswz],
                 &As[g * 2048 + wbase]);
    }
#pragma unroll
    for (int g = 0; g < 4; g++)
      gl_lds16(&B[(long)(n0 + g * 32 + srow) * K + k0 + kswz],
               &Bs[g * 2048 + wbase]);
    __syncthreads();
#pragma unroll
    for (int kk = 0; kk < 2; kk++) {
      short8 a[4], b[4];
#pragma unroll
      for (int i = 0; i < 4; i++)
        a[i] = *(const short8*)&As[(wm + i * 16 + l15) * 64 + ((kk * 4 + quad) ^ (l15 & 7)) * 8];
#pragma unroll
      for (int j = 0; j < 4; j++)
        b[j] = *(const short8*)&Bs[(wn + j * 16 + l15) * 64 + ((kk * 4 + quad) ^ (l15 & 7)) * 8];
#pragma unroll
      for (int i = 0; i < 4; i++)
#pragma unroll
        for (int j = 0; j < 4; j++)
          acc[i][j] = __builtin_amdgcn_mfma_f32_16x16x32_bf16(a[i], b[j], acc[i][j], 0, 0, 0);
    }
  }

  const int gidx = w >> 1;
  for (int i = 0; i < 4; i++) {
    __syncthreads();
    if (c_f32) {
      float* scr = (float*)As;
#pragma unroll
      for (int j = 0; j < 4; j++) {
        const int col = wn + j * 16 + l15;
        const float bv = bias ? bias[n0 + col] : 0.0f;
#pragma unroll
        for (int r = 0; r < 4; r++) {
          const int row = gidx * 16 + quad * 4 + r;
          scr[row * 128 + (col ^ ((row & 7) << 4))] = acc[i][j][r] + bv;
        }
      }
    } else {
#pragma unroll
      for (int j = 0; j < 4; j++) {
        const int col = wn + j * 16 + l15;
#pragma unroll
        for (int r = 0; r < 4; r++) {
          const int row = gidx * 16 + quad * 4 + r;
          As[row * 128 + (col ^ ((row & 7) << 4))] = f2b(acc[i][j][r]);
        }
      }
    }
    __syncthreads();
    const int rs   = tid >> 3;
    const int colp = (tid & 7) * 16;
    const int cs   = colp ^ ((rs & 7) << 4);
    const long row_g = m0 + (rs >> 4) * 64 + i * 16 + (rs & 15);
    if (c_f32) {
      float* C = (float*)Cv;
      const float* scr = (const float*)As;
#pragma unroll
      for (int q = 0; q < 4; q++) {
        float4_ v = *(const float4_*)&scr[rs * 128 + cs + q * 4];
        *(float4_*)&C[row_g * ldc + n0 + colp + q * 4] = v;
      }
    } else {
      short* C = (short*)Cv;
      short8 v0 = *(const short8*)&As[rs * 128 + cs];
      short8 v1 = *(const short8*)&As[rs * 128 + cs + 8];
      *(short8*)&C[row_g * ldc + n0 + colp]     = v0;
      *(short8*)&C[row_g * ldc + n0 + colp + 8] = v1;
    }
  }
}

// Block-diagonal causal attention, causal-split, 512 threads (2 wave-groups).
// (Verified R5 code, unchanged.)
template<int NJ>  // NJ = NK/16
__device__ __forceinline__ void attn_body(short* __restrict__ qkv, int tile,
                                          short* smem)
{
  constexpr int NK    = NJ * 16;          // 64 or 128
  constexpr int QROW0 = (NJ == 8) ? 64 : 0;
  constexpr int KCALLS = NK / 32;

  short* Ps = smem;                       // [64*136] bf16 P (phase 2 -> 3)
  short* U  = smem + 8704;                // overlaid union region

  const int tid  = threadIdx.x;
  const int t8   = tid & 255;
  const int g    = tid >> 8;
  const int wl   = (tid >> 6) & 3;
  const int lane = tid & 63;
  const int quad = lane >> 4;
  const int l15  = lane & 15;
  const long base = (long)tile * 128 * 3072;

  const short* Qg = qkv + base + (long)QROW0 * 3072;
  const short* Kg = qkv + base + 1024;
  const short* Vg = qkv + base + 2048;

  // ---- Phase 1: S = Q K^T, split-K across groups. K-step 64, XOR swizzle.
  short* Qs = U + g * 4096;
  short* Ks = U + 8192 + g * 8192;
  const int srow8 = t8 >> 3;
  const int sk    = t8 & 7;
  const int kswz  = (sk ^ (srow8 & 7)) * 8;
  const int wb    = wl * 512;

  float4_ acc[NJ] = {};

  for (int i = 0; i < 8; i++) {
    const int k0 = g * 64 + i * 128;
    __syncthreads();
#pragma unroll
    for (int c = 0; c < 2; c++)
      gl_lds16(&Qg[(long)(c * 32 + srow8) * 3072 + k0 + kswz], &Qs[c * 2048 + wb]);
#pragma unroll
    for (int c = 0; c < KCALLS; c++)
      gl_lds16(&Kg[(long)(c * 32 + srow8) * 3072 + k0 + kswz], &Ks[c * 2048 + wb]);
    __syncthreads();
#pragma unroll
    for (int kk = 0; kk < 2; kk++) {
      const int ch = ((kk * 4 + quad) ^ (l15 & 7)) * 8;
      short8 a = *(const short8*)&Qs[(wl * 16 + l15) * 64 + ch];
#pragma unroll
      for (int j = 0; j < NJ; j++) {
        short8 b = *(const short8*)&Ks[(j * 16 + l15) * 64 + ch];
        acc[j] = __builtin_amdgcn_mfma_f32_16x16x32_bf16(a, b, acc[j], 0, 0, 0);
      }
    }
  }
  __syncthreads();

  // ---- Phase 2: sum partials, mask + softmax (group 0).
  float* Sscr = (float*)U;
  if (g == 1) {
#pragma unroll
    for (int r = 0; r < 4; r++) {
      const int rowq = wl * 16 + quad * 4 + r;
#pragma unroll
      for (int j = 0; j < NJ; j++)
        Sscr[rowq * 132 + j * 16 + l15] = acc[j][r];
    }
  }
  __syncthreads();
  if (g == 0) {
    const float scale = 0.03125f;  // 1024^-0.5
#pragma unroll
    for (int r = 0; r < 4; r++) {
      const int rowq = wl * 16 + quad * 4 + r;
      float s[NJ];
      float mx = -3.0e38f;
#pragma unroll
      for (int j = 0; j < NJ; j++) {
        const int col = j * 16 + l15;
        const float v = (acc[j][r] + Sscr[rowq * 132 + col]) * scale;
        s[j] = (col <= QROW0 + rowq) ? v : -3.0e38f;
        mx = fmaxf(mx, s[j]);
      }
      mx = fmaxf(mx, __shfl_xor(mx, 1));
      mx = fmaxf(mx, __shfl_xor(mx, 2));
      mx = fmaxf(mx, __shfl_xor(mx, 4));
      mx = fmaxf(mx, __shfl_xor(mx, 8));
      float p[NJ];
      float sum = 0.0f;
#pragma unroll
      for (int j = 0; j < NJ; j++) {
        p[j] = (s[j] > -1.0e38f) ? __expf(s[j] - mx) : 0.0f;
        sum += p[j];
      }
      sum += __shfl_xor(sum, 1);
      sum += __shfl_xor(sum, 2);
      sum += __shfl_xor(sum, 4);
      sum += __shfl_xor(sum, 8);
      const float inv = 1.0f / (sum + 1e-6f);
#pragma unroll
      for (int j = 0; j < NJ; j++)
        Ps[rowq * 136 + j * 16 + l15] = f2b(p[j] * inv);
    }
  }
  __syncthreads();

  // ---- Phase 3: O = P V, split-D across groups.
  short* Vt = U + g * 8704;
  short* Ot = U + 17408 + g * 4608;
  short* Op = qkv + base + (long)QROW0 * 3072;

  for (int i = 0; i < 8; i++) {
    const int d0 = g * 64 + i * 128;
    __syncthreads();
    if (NJ == 8) {
      const int kr = t8 >> 1, dp = (t8 & 1) * 32;
#pragma unroll
      for (int gg = 0; gg < 4; gg++) {
        short8 v = *(const short8*)&Vg[(long)kr * 3072 + d0 + dp + gg * 8];
#pragma unroll
        for (int t = 0; t < 8; t++) Vt[(dp + gg * 8 + t) * 136 + kr] = v[t];
      }
    } else {
      const int kr = t8 >> 2, dp = (t8 & 3) * 16;
#pragma unroll
      for (int gg = 0; gg < 2; gg++) {
        short8 v = *(const short8*)&Vg[(long)kr * 3072 + d0 + dp + gg * 8];
#pragma unroll
        for (int t = 0; t < 8; t++) Vt[(dp + gg * 8 + t) * 136 + kr] = v[t];
      }
    }
    __syncthreads();
    float4_ o[4] = {};
#pragma unroll
    for (int kk = 0; kk < NK / 32; kk++) {
      short8 a = *(const short8*)&Ps[(wl * 16 + l15) * 136 + kk * 32 + quad * 8];
#pragma unroll
      for (int j = 0; j < 4; j++) {
        short8 b = *(const short8*)&Vt[(j * 16 + l15) * 136 + kk * 32 + quad * 8];
        o[j] = __builtin_amdgcn_mfma_f32_16x16x32_bf16(a, b, o[j], 0, 0, 0);
      }
    }
#pragma unroll
    for (int j = 0; j < 4; j++)
#pragma unroll
      for (int r = 0; r < 4; r++)
        Ot[(wl * 16 + quad * 4 + r) * 72 + j * 16 + l15] = f2b(o[j][r]);
    __syncthreads();
    const int orow = t8 >> 2, ocp = (t8 & 3) * 16;
    short8 v0 = *(const short8*)&Ot[orow * 72 + ocp];
    short8 v1 = *(const short8*)&Ot[orow * 72 + ocp + 8];
    *(short8*)&Op[(long)orow * 3072 + d0 + ocp]     = v0;
    *(short8*)&Op[(long)orow * 3072 + d0 + ocp + 8] = v1;
  }
}

__global__ __launch_bounds__(512) void attn_blockdiag(short* __restrict__ qkv)
{
  __shared__ __align__(16) short smem[35328];
  const int tile = blockIdx.x >> 1;
  if (blockIdx.x & 1) attn_body<8>(qkv, tile, smem);
  else                attn_body<4>(qkv, tile, smem);
}

extern "C" void kernel_launch(void* const* d_in, const int* in_sizes, int n_in,
                              void* d_out, int out_size, void* d_ws, size_t ws_size,
                              hipStream_t stream) {
  // Inputs fp32; OUTPUT fp32 (reference returns fp32).
  const float* x    = (const float*)d_in[0];  // [4,4096,1024]
  const float* Wqkv = (const float*)d_in[1];  // [1024,3072]
  const float* Wout = (const float*)d_in[2];  // [1024,1024] (= [N][K] for @W_out^T)
  const float* bout = (const float*)d_in[3];  // [1024]
  float* out = (float*)d_out;                 // [4,4096,1024] fp32

  char* ws = (char*)d_ws;
  short* WqkvT = (short*)ws;                    // [3072][1024] bf16:  6,291,456 B
  short* Woutb = (short*)(ws + 6291456);        // [1024][1024] bf16:  2,097,152 B
  short* qkv   = (short*)(ws + 8388608);        // bf16, up to [16384][3072]
  short* xb    = (short*)(ws + 8388608 + (size_t)16384 * 3072 * 2);  // [16384][1024]

  if (ws_size >= 8388608 + (size_t)16384 * 3072 * 2 + (size_t)16384 * 1024 * 2) {
    // Tier A (143 MB): fused prep, pipelined bf16 GEMMs, split attn.
    prep<<<9472, 256, 0, stream>>>(Wqkv, WqkvT, Wout, Woutb, x, xb, 1);
    gemm_bt_p<<<dim3(24, 128), 256, 0, stream>>>(xb, 1024, WqkvT,
                                                 qkv, 3072, 0, 1024, nullptr);
    attn_blockdiag<<<dim3(256), 512, 0, stream>>>(qkv);
    gemm_bt_p<<<dim3(8, 128), 256, 0, stream>>>(qkv, 3072, Woutb,
                                                out, 1024, 1, 1024, bout);
  } else if (ws_size >= 8388608 + (size_t)16384 * 3072 * 2) {
    // Tier B (109 MB): gemm1 converts x fp32 -> bf16 while staging.
    prep<<<1280, 256, 0, stream>>>(Wqkv, WqkvT, Wout, Woutb, nullptr, nullptr, 0);
    gemm_bt<<<dim3(24, 128), 256, 0, stream>>>(x, 1024, 1, WqkvT,
                                               qkv, 3072, 0, 1024, nullptr);
    attn_blockdiag<<<dim3(256), 512, 0, stream>>>(qkv);
    gemm_bt_p<<<dim3(8, 128), 256, 0, stream>>>(qkv, 3072, Woutb,
                                                out, 1024, 1, 1024, bout);
  } else {
    // Tier C (34 MB): per-batch chunks of 4096 rows.
    prep<<<1280, 256, 0, stream>>>(Wqkv, WqkvT, Wout, Woutb, nullptr, nullptr, 0);
    for (int c = 0; c < 4; c++) {
      const float* xc = x + (long)c * 4096 * 1024;
      float* outc = out + (long)c * 4096 * 1024;
      gemm_bt<<<dim3(24, 32), 256, 0, stream>>>(xc, 1024, 1, WqkvT,
                                                qkv, 3072, 0, 1024, nullptr);
      attn_blockdiag<<<dim3(64), 512, 0, stream>>>(qkv);
      gemm_bt_p<<<dim3(8, 32), 256, 0, stream>>>(qkv, 3072, Woutb,
                                                 outc, 1024, 1, 1024, bout);
    }
  }
}

// Round 8
// 356.636 us; speedup vs baseline: 7.8525x; 7.8525x over previous
//
#include <hip/hip_runtime.h>
#include <hip/hip_bf16.h>

typedef __attribute__((ext_vector_type(8))) short short8;
typedef __attribute__((ext_vector_type(4))) float float4_;

typedef const __attribute__((address_space(1))) void* gas_t;
typedef __attribute__((address_space(3))) void* las_t;

// Async global->LDS, 16 B/lane. LDS dest is wave-uniform base + lane*16.
__device__ __forceinline__ void gl_lds16(const void* g, void* l) {
  __builtin_amdgcn_global_load_lds((gas_t)g, (las_t)l, 16, 0, 0);
}

__device__ __forceinline__ short f2b(float f) {
  union { __hip_bfloat16 h; short s; } u;
  u.h = __float2bfloat16(f);
  return u.s;
}
__device__ __forceinline__ short8 cvt8(float4_ lo, float4_ hi) {
  short8 r;
#pragma unroll
  for (int t = 0; t < 4; t++) { r[t] = f2b(lo[t]); r[t + 4] = f2b(hi[t]); }
  return r;
}

// Fused prep: [0,768) transpose Wqkv -> WqkvT (bf16, [3072][1024]);
// [768,1280) convert Wout -> bf16; [1280,...) convert x -> bf16 (if has_x).
__global__ __launch_bounds__(256) void prep(
    const float* __restrict__ Wqkv, short* __restrict__ WqkvT,
    const float* __restrict__ Wout, short* __restrict__ Woutb,
    const float* __restrict__ x, short* __restrict__ xb, int has_x)
{
  __shared__ __align__(16) short T[64 * 72];
  const int b   = blockIdx.x;
  const int tid = threadIdx.x;
  if (b < 768) {
    const int R = 1024, C = 3072;
    const int r0 = (b / 48) * 64;
    const int c0 = (b % 48) * 64;
    const int r  = tid >> 2;
    const int cp = (tid & 3) * 16;
#pragma unroll
    for (int g = 0; g < 4; g++) {
      float4_ v = *(const float4_*)&Wqkv[(long)(r0 + r) * C + c0 + cp + g * 4];
#pragma unroll
      for (int t = 0; t < 4; t++) T[(cp + g * 4 + t) * 72 + r] = f2b(v[t]);
    }
    __syncthreads();
    const int c  = tid >> 2;
    const int rp = (tid & 3) * 16;
    short8 w0 = *(const short8*)&T[c * 72 + rp];
    short8 w1 = *(const short8*)&T[c * 72 + rp + 8];
    *(short8*)&WqkvT[(long)(c0 + c) * R + r0 + rp] = w0;
    *(short8*)&WqkvT[(long)(c0 + c) * R + r0 + rp + 8] = w1;
  } else if (b < 1280) {
    const long i = ((long)(b - 768) * 256 + tid) * 8;
    float4_ lo = *(const float4_*)&Wout[i];
    float4_ hi = *(const float4_*)&Wout[i + 4];
    *(short8*)&Woutb[i] = cvt8(lo, hi);
  } else if (has_x) {
    const long i = ((long)(b - 1280) * 256 + tid) * 8;
    float4_ lo = *(const float4_*)&x[i];
    float4_ hi = *(const float4_*)&x[i + 4];
    *(short8*)&xb[i] = cvt8(lo, hi);
  }
}

// ============================================================================
// gemm_bt_p: C[M,N] = A[M,K] @ B[N,K]^T (+bias), A,B bf16. 128x128 tile,
// 4 waves (2x2 of 64x64), BK=32, double-buffered LDS, pipelined: tile t+1's
// global_load_lds issued BEFORE tile t's compute; ONE __syncthreads()/K-step.
// 64 B LDS rows: chunk-XOR swizzle (chunk ^= (row>>1)&3) applied both-sides.
// XCD-bijective block swizzle. R7 post-mortem fix: epilogue loops FULLY
// UNROLLED (rule #20 — runtime-indexed acc[i] demoted the whole accumulator
// to scratch: VGPR 44, 10 GB/dispatch spill traffic, 2% MfmaUtil).
// ============================================================================
__global__ __launch_bounds__(256) void gemm_bt_p(
    const short* __restrict__ A, int lda,
    const short* __restrict__ B,
    void* __restrict__ Cv, int ldc, int c_f32,
    int K, const float* __restrict__ bias)
{
  __shared__ __align__(16) short As[2][128 * 32];  // 16 KB (epilogue scratch too)
  __shared__ __align__(16) short Bs[2][128 * 32];  // 16 KB
  const int tid  = threadIdx.x;
  const int lane = tid & 63;
  const int w    = tid >> 6;
  const int quad = lane >> 4;
  const int l15  = lane & 15;
  const int wm   = (w >> 1) * 64;
  const int wn   = (w & 1) * 64;

  const int nx  = gridDim.x;
  const int nwg = nx * gridDim.y;
  int wid = blockIdx.y * nx + blockIdx.x;
  if ((nwg & 7) == 0) wid = (wid & 7) * (nwg >> 3) + (wid >> 3);
  const int m0 = (wid / nx) * 128;
  const int n0 = (wid % nx) * 128;

  float4_ acc[4][4] = {};

  // staging: 2 calls/operand; call g covers rows g*64 + (tid>>2).
  const int srow  = tid >> 2;                          // 0..63
  const int kswz  = (((tid & 3) ^ ((srow >> 1) & 3)) * 8);  // pre-swizzled src
  const int wbase = w * 512;                           // linear dest, lane*8
  const int rsz   = ((l15 >> 1) & 3);                  // read-side swizzle

  const int nt = K >> 5;                               // 32-wide K-steps

  // prologue: stage tile 0 into buffer 0
  gl_lds16(&A[(long)(m0 + srow) * lda + kswz],      &As[0][wbase]);
  gl_lds16(&A[(long)(m0 + 64 + srow) * lda + kswz], &As[0][2048 + wbase]);
  gl_lds16(&B[(long)(n0 + srow) * K + kswz],        &Bs[0][wbase]);
  gl_lds16(&B[(long)(n0 + 64 + srow) * K + kswz],   &Bs[0][2048 + wbase]);
  __syncthreads();

  int cur = 0;
#pragma unroll 1
  for (int t = 0; t < nt; ++t) {
    if (t + 1 < nt) {
      const long k1 = (long)(t + 1) << 5;
      gl_lds16(&A[(long)(m0 + srow) * lda + k1 + kswz],      &As[cur ^ 1][wbase]);
      gl_lds16(&A[(long)(m0 + 64 + srow) * lda + k1 + kswz], &As[cur ^ 1][2048 + wbase]);
      gl_lds16(&B[(long)(n0 + srow) * K + k1 + kswz],        &Bs[cur ^ 1][wbase]);
      gl_lds16(&B[(long)(n0 + 64 + srow) * K + k1 + kswz],   &Bs[cur ^ 1][2048 + wbase]);
    }
    short8 a[4], b[4];
#pragma unroll
    for (int i = 0; i < 4; i++)
      a[i] = *(const short8*)&As[cur][(wm + i * 16 + l15) * 32 + ((quad ^ rsz) * 8)];
#pragma unroll
    for (int j = 0; j < 4; j++)
      b[j] = *(const short8*)&Bs[cur][(wn + j * 16 + l15) * 32 + ((quad ^ rsz) * 8)];
#pragma unroll
    for (int i = 0; i < 4; i++)
#pragma unroll
      for (int j = 0; j < 4; j++)
        acc[i][j] = __builtin_amdgcn_mfma_f32_16x16x32_bf16(a[i], b[j], acc[i][j], 0, 0, 0);
    __syncthreads();  // t+1 loads landed; all waves' reads of buf cur done
    cur ^= 1;
  }

  // Epilogue: per i-strip, transpose acc through LDS scratch (XOR-swizzled),
  // coalesced float4/short8 stores. FULLY UNROLLED: acc indices must be
  // compile-time constants (rule #20).
  float* scrf = (float*)As;      // [32][128] fp32 = 16 KB
  short* scrh = (short*)As;      // [32][128] bf16 =  8 KB
  const int gidx = w >> 1;
#pragma unroll
  for (int i = 0; i < 4; i++) {
    __syncthreads();
    if (c_f32) {
#pragma unroll
      for (int j = 0; j < 4; j++) {
        const int col = wn + j * 16 + l15;
        const float bv = bias ? bias[n0 + col] : 0.0f;
#pragma unroll
        for (int r = 0; r < 4; r++) {
          const int row = gidx * 16 + quad * 4 + r;
          scrf[row * 128 + (col ^ ((row & 7) << 4))] = acc[i][j][r] + bv;
        }
      }
    } else {
#pragma unroll
      for (int j = 0; j < 4; j++) {
        const int col = wn + j * 16 + l15;
#pragma unroll
        for (int r = 0; r < 4; r++) {
          const int row = gidx * 16 + quad * 4 + r;
          scrh[row * 128 + (col ^ ((row & 7) << 4))] = f2b(acc[i][j][r]);
        }
      }
    }
    __syncthreads();
    const int rs   = tid >> 3;          // 0..31
    const int colp = (tid & 7) * 16;    // 0..112
    const int cs   = colp ^ ((rs & 7) << 4);
    const long row_g = m0 + (rs >> 4) * 64 + i * 16 + (rs & 15);
    if (c_f32) {
      float* C = (float*)Cv;
#pragma unroll
      for (int q = 0; q < 4; q++)
        *(float4_*)&C[row_g * ldc + n0 + colp + q * 4] =
            *(const float4_*)&scrf[rs * 128 + cs + q * 4];
    } else {
      short* C = (short*)Cv;
      *(short8*)&C[row_g * ldc + n0 + colp]     = *(const short8*)&scrh[rs * 128 + cs];
      *(short8*)&C[row_g * ldc + n0 + colp + 8] = *(const short8*)&scrh[rs * 128 + cs + 8];
    }
  }
}

// C[M,N] = A[M,K] @ B[N,K]^T, A fp32 (reg-staged+converted) or bf16. 128x128
// tile, 4 waves, BK=64, chunk-XOR swizzle. (Verified R4/R5 code, unchanged —
// used for fp32-A tiers.)
__global__ __launch_bounds__(256) void gemm_bt(
    const void* __restrict__ Av, int lda, int a_f32,
    const short* __restrict__ B,
    void* __restrict__ Cv, int ldc, int c_f32,
    int K, const float* __restrict__ bias)
{
  __shared__ __align__(16) short As[128 * 64];
  __shared__ __align__(16) short Bs[128 * 64];
  const int tid  = threadIdx.x;
  const int lane = tid & 63;
  const int w    = tid >> 6;
  const int quad = lane >> 4;
  const int l15  = lane & 15;
  const int wm   = (w >> 1) * 64;
  const int wn   = (w & 1) * 64;

  const int nx  = gridDim.x;
  const int nwg = nx * gridDim.y;
  int wid = blockIdx.y * nx + blockIdx.x;
  if ((nwg & 7) == 0) wid = (wid & 7) * (nwg >> 3) + (wid >> 3);
  const int m0 = (wid / nx) * 128;
  const int n0 = (wid % nx) * 128;

  float4_ acc[4][4] = {};

  const int srow = tid >> 3;
  const int sk   = tid & 7;
  const int kswz = ((sk ^ (srow & 7)) * 8);
  const int wbase = w * 512;
  const int frow = tid >> 1;
  const int fh   = tid & 1;

  for (int k0 = 0; k0 < K; k0 += 64) {
    short8 fs[4];
    if (a_f32) {
      const float* Af = (const float*)Av;
#pragma unroll
      for (int g = 0; g < 2; g++) {
        float4_ v0 = *(const float4_*)&Af[(long)(m0 + frow) * lda + k0 + fh * 32 + g * 16];
        float4_ v1 = *(const float4_*)&Af[(long)(m0 + frow) * lda + k0 + fh * 32 + g * 16 + 4];
        float4_ v2 = *(const float4_*)&Af[(long)(m0 + frow) * lda + k0 + fh * 32 + g * 16 + 8];
        float4_ v3 = *(const float4_*)&Af[(long)(m0 + frow) * lda + k0 + fh * 32 + g * 16 + 12];
        fs[g * 2]     = cvt8(v0, v1);
        fs[g * 2 + 1] = cvt8(v2, v3);
      }
    }
    __syncthreads();
    if (a_f32) {
#pragma unroll
      for (int g = 0; g < 4; g++) {
        const int c_log = fh * 4 + g;
        *(short8*)&As[frow * 64 + ((c_log ^ (frow & 7)) * 8)] = fs[g];
      }
    } else {
      const short* Ab = (const short*)Av;
#pragma unroll
      for (int g = 0; g < 4; g++)
        gl_lds16(&Ab[(long)(m0 + g * 32 + srow) * lda + k0 + kswz],
                 &As[g * 2048 + wbase]);
    }
#pragma unroll
    for (int g = 0; g < 4; g++)
      gl_lds16(&B[(long)(n0 + g * 32 + srow) * K + k0 + kswz],
               &Bs[g * 2048 + wbase]);
    __syncthreads();
#pragma unroll
    for (int kk = 0; kk < 2; kk++) {
      short8 a[4], b[4];
#pragma unroll
      for (int i = 0; i < 4; i++)
        a[i] = *(const short8*)&As[(wm + i * 16 + l15) * 64 + ((kk * 4 + quad) ^ (l15 & 7)) * 8];
#pragma unroll
      for (int j = 0; j < 4; j++)
        b[j] = *(const short8*)&Bs[(wn + j * 16 + l15) * 64 + ((kk * 4 + quad) ^ (l15 & 7)) * 8];
#pragma unroll
      for (int i = 0; i < 4; i++)
#pragma unroll
        for (int j = 0; j < 4; j++)
          acc[i][j] = __builtin_amdgcn_mfma_f32_16x16x32_bf16(a[i], b[j], acc[i][j], 0, 0, 0);
    }
  }

  const int gidx = w >> 1;
#pragma unroll
  for (int i = 0; i < 4; i++) {
    __syncthreads();
    if (c_f32) {
      float* scr = (float*)As;
#pragma unroll
      for (int j = 0; j < 4; j++) {
        const int col = wn + j * 16 + l15;
        const float bv = bias ? bias[n0 + col] : 0.0f;
#pragma unroll
        for (int r = 0; r < 4; r++) {
          const int row = gidx * 16 + quad * 4 + r;
          scr[row * 128 + (col ^ ((row & 7) << 4))] = acc[i][j][r] + bv;
        }
      }
    } else {
#pragma unroll
      for (int j = 0; j < 4; j++) {
        const int col = wn + j * 16 + l15;
#pragma unroll
        for (int r = 0; r < 4; r++) {
          const int row = gidx * 16 + quad * 4 + r;
          As[row * 128 + (col ^ ((row & 7) << 4))] = f2b(acc[i][j][r]);
        }
      }
    }
    __syncthreads();
    const int rs   = tid >> 3;
    const int colp = (tid & 7) * 16;
    const int cs   = colp ^ ((rs & 7) << 4);
    const long row_g = m0 + (rs >> 4) * 64 + i * 16 + (rs & 15);
    if (c_f32) {
      float* C = (float*)Cv;
      const float* scr = (const float*)As;
#pragma unroll
      for (int q = 0; q < 4; q++) {
        float4_ v = *(const float4_*)&scr[rs * 128 + cs + q * 4];
        *(float4_*)&C[row_g * ldc + n0 + colp + q * 4] = v;
      }
    } else {
      short* C = (short*)Cv;
      short8 v0 = *(const short8*)&As[rs * 128 + cs];
      short8 v1 = *(const short8*)&As[rs * 128 + cs + 8];
      *(short8*)&C[row_g * ldc + n0 + colp]     = v0;
      *(short8*)&C[row_g * ldc + n0 + colp + 8] = v1;
    }
  }
}

// Block-diagonal causal attention, causal-split, 512 threads (2 wave-groups).
// (Verified R5 code, unchanged.)
template<int NJ>  // NJ = NK/16
__device__ __forceinline__ void attn_body(short* __restrict__ qkv, int tile,
                                          short* smem)
{
  constexpr int NK    = NJ * 16;          // 64 or 128
  constexpr int QROW0 = (NJ == 8) ? 64 : 0;
  constexpr int KCALLS = NK / 32;

  short* Ps = smem;                       // [64*136] bf16 P (phase 2 -> 3)
  short* U  = smem + 8704;                // overlaid union region

  const int tid  = threadIdx.x;
  const int t8   = tid & 255;
  const int g    = tid >> 8;
  const int wl   = (tid >> 6) & 3;
  const int lane = tid & 63;
  const int quad = lane >> 4;
  const int l15  = lane & 15;
  const long base = (long)tile * 128 * 3072;

  const short* Qg = qkv + base + (long)QROW0 * 3072;
  const short* Kg = qkv + base + 1024;
  const short* Vg = qkv + base + 2048;

  // ---- Phase 1: S = Q K^T, split-K across groups. K-step 64, XOR swizzle.
  short* Qs = U + g * 4096;
  short* Ks = U + 8192 + g * 8192;
  const int srow8 = t8 >> 3;
  const int sk    = t8 & 7;
  const int kswz  = (sk ^ (srow8 & 7)) * 8;
  const int wb    = wl * 512;

  float4_ acc[NJ] = {};

  for (int i = 0; i < 8; i++) {
    const int k0 = g * 64 + i * 128;
    __syncthreads();
#pragma unroll
    for (int c = 0; c < 2; c++)
      gl_lds16(&Qg[(long)(c * 32 + srow8) * 3072 + k0 + kswz], &Qs[c * 2048 + wb]);
#pragma unroll
    for (int c = 0; c < KCALLS; c++)
      gl_lds16(&Kg[(long)(c * 32 + srow8) * 3072 + k0 + kswz], &Ks[c * 2048 + wb]);
    __syncthreads();
#pragma unroll
    for (int kk = 0; kk < 2; kk++) {
      const int ch = ((kk * 4 + quad) ^ (l15 & 7)) * 8;
      short8 a = *(const short8*)&Qs[(wl * 16 + l15) * 64 + ch];
#pragma unroll
      for (int j = 0; j < NJ; j++) {
        short8 b = *(const short8*)&Ks[(j * 16 + l15) * 64 + ch];
        acc[j] = __builtin_amdgcn_mfma_f32_16x16x32_bf16(a, b, acc[j], 0, 0, 0);
      }
    }
  }
  __syncthreads();

  // ---- Phase 2: sum partials, mask + softmax (group 0).
  float* Sscr = (float*)U;
  if (g == 1) {
#pragma unroll
    for (int r = 0; r < 4; r++) {
      const int rowq = wl * 16 + quad * 4 + r;
#pragma unroll
      for (int j = 0; j < NJ; j++)
        Sscr[rowq * 132 + j * 16 + l15] = acc[j][r];
    }
  }
  __syncthreads();
  if (g == 0) {
    const float scale = 0.03125f;  // 1024^-0.5
#pragma unroll
    for (int r = 0; r < 4; r++) {
      const int rowq = wl * 16 + quad * 4 + r;
      float s[NJ];
      float mx = -3.0e38f;
#pragma unroll
      for (int j = 0; j < NJ; j++) {
        const int col = j * 16 + l15;
        const float v = (acc[j][r] + Sscr[rowq * 132 + col]) * scale;
        s[j] = (col <= QROW0 + rowq) ? v : -3.0e38f;
        mx = fmaxf(mx, s[j]);
      }
      mx = fmaxf(mx, __shfl_xor(mx, 1));
      mx = fmaxf(mx, __shfl_xor(mx, 2));
      mx = fmaxf(mx, __shfl_xor(mx, 4));
      mx = fmaxf(mx, __shfl_xor(mx, 8));
      float p[NJ];
      float sum = 0.0f;
#pragma unroll
      for (int j = 0; j < NJ; j++) {
        p[j] = (s[j] > -1.0e38f) ? __expf(s[j] - mx) : 0.0f;
        sum += p[j];
      }
      sum += __shfl_xor(sum, 1);
      sum += __shfl_xor(sum, 2);
      sum += __shfl_xor(sum, 4);
      sum += __shfl_xor(sum, 8);
      const float inv = 1.0f / (sum + 1e-6f);
#pragma unroll
      for (int j = 0; j < NJ; j++)
        Ps[rowq * 136 + j * 16 + l15] = f2b(p[j] * inv);
    }
  }
  __syncthreads();

  // ---- Phase 3: O = P V, split-D across groups.
  short* Vt = U + g * 8704;
  short* Ot = U + 17408 + g * 4608;
  short* Op = qkv + base + (long)QROW0 * 3072;

  for (int i = 0; i < 8; i++) {
    const int d0 = g * 64 + i * 128;
    __syncthreads();
    if (NJ == 8) {
      const int kr = t8 >> 1, dp = (t8 & 1) * 32;
#pragma unroll
      for (int gg = 0; gg < 4; gg++) {
        short8 v = *(const short8*)&Vg[(long)kr * 3072 + d0 + dp + gg * 8];
#pragma unroll
        for (int t = 0; t < 8; t++) Vt[(dp + gg * 8 + t) * 136 + kr] = v[t];
      }
    } else {
      const int kr = t8 >> 2, dp = (t8 & 3) * 16;
#pragma unroll
      for (int gg = 0; gg < 2; gg++) {
        short8 v = *(const short8*)&Vg[(long)kr * 3072 + d0 + dp + gg * 8];
#pragma unroll
        for (int t = 0; t < 8; t++) Vt[(dp + gg * 8 + t) * 136 + kr] = v[t];
      }
    }
    __syncthreads();
    float4_ o[4] = {};
#pragma unroll
    for (int kk = 0; kk < NK / 32; kk++) {
      short8 a = *(const short8*)&Ps[(wl * 16 + l15) * 136 + kk * 32 + quad * 8];
#pragma unroll
      for (int j = 0; j < 4; j++) {
        short8 b = *(const short8*)&Vt[(j * 16 + l15) * 136 + kk * 32 + quad * 8];
        o[j] = __builtin_amdgcn_mfma_f32_16x16x32_bf16(a, b, o[j], 0, 0, 0);
      }
    }
#pragma unroll
    for (int j = 0; j < 4; j++)
#pragma unroll
      for (int r = 0; r < 4; r++)
        Ot[(wl * 16 + quad * 4 + r) * 72 + j * 16 + l15] = f2b(o[j][r]);
    __syncthreads();
    const int orow = t8 >> 2, ocp = (t8 & 3) * 16;
    short8 v0 = *(const short8*)&Ot[orow * 72 + ocp];
    short8 v1 = *(const short8*)&Ot[orow * 72 + ocp + 8];
    *(short8*)&Op[(long)orow * 3072 + d0 + ocp]     = v0;
    *(short8*)&Op[(long)orow * 3072 + d0 + ocp + 8] = v1;
  }
}

__global__ __launch_bounds__(512) void attn_blockdiag(short* __restrict__ qkv)
{
  __shared__ __align__(16) short smem[35328];
  const int tile = blockIdx.x >> 1;
  if (blockIdx.x & 1) attn_body<8>(qkv, tile, smem);
  else                attn_body<4>(qkv, tile, smem);
}

extern "C" void kernel_launch(void* const* d_in, const int* in_sizes, int n_in,
                              void* d_out, int out_size, void* d_ws, size_t ws_size,
                              hipStream_t stream) {
  // Inputs fp32; OUTPUT fp32 (reference returns fp32).
  const float* x    = (const float*)d_in[0];  // [4,4096,1024]
  const float* Wqkv = (const float*)d_in[1];  // [1024,3072]
  const float* Wout = (const float*)d_in[2];  // [1024,1024] (= [N][K] for @W_out^T)
  const float* bout = (const float*)d_in[3];  // [1024]
  float* out = (float*)d_out;                 // [4,4096,1024] fp32

  char* ws = (char*)d_ws;
  short* WqkvT = (short*)ws;                    // [3072][1024] bf16:  6,291,456 B
  short* Woutb = (short*)(ws + 6291456);        // [1024][1024] bf16:  2,097,152 B
  short* qkv   = (short*)(ws + 8388608);        // bf16, up to [16384][3072]
  short* xb    = (short*)(ws + 8388608 + (size_t)16384 * 3072 * 2);  // [16384][1024]

  if (ws_size >= 8388608 + (size_t)16384 * 3072 * 2 + (size_t)16384 * 1024 * 2) {
    // Tier A (143 MB): fused prep, pipelined bf16 GEMMs, split attn.
    prep<<<9472, 256, 0, stream>>>(Wqkv, WqkvT, Wout, Woutb, x, xb, 1);
    gemm_bt_p<<<dim3(24, 128), 256, 0, stream>>>(xb, 1024, WqkvT,
                                                 qkv, 3072, 0, 1024, nullptr);
    attn_blockdiag<<<dim3(256), 512, 0, stream>>>(qkv);
    gemm_bt_p<<<dim3(8, 128), 256, 0, stream>>>(qkv, 3072, Woutb,
                                                out, 1024, 1, 1024, bout);
  } else if (ws_size >= 8388608 + (size_t)16384 * 3072 * 2) {
    // Tier B (109 MB): gemm1 converts x fp32 -> bf16 while staging.
    prep<<<1280, 256, 0, stream>>>(Wqkv, WqkvT, Wout, Woutb, nullptr, nullptr, 0);
    gemm_bt<<<dim3(24, 128), 256, 0, stream>>>(x, 1024, 1, WqkvT,
                                               qkv, 3072, 0, 1024, nullptr);
    attn_blockdiag<<<dim3(256), 512, 0, stream>>>(qkv);
    gemm_bt_p<<<dim3(8, 128), 256, 0, stream>>>(qkv, 3072, Woutb,
                                                out, 1024, 1, 1024, bout);
  } else {
    // Tier C (34 MB): per-batch chunks of 4096 rows.
    prep<<<1280, 256, 0, stream>>>(Wqkv, WqkvT, Wout, Woutb, nullptr, nullptr, 0);
    for (int c = 0; c < 4; c++) {
      const float* xc = x + (long)c * 4096 * 1024;
      float* outc = out + (long)c * 4096 * 1024;
      gemm_bt<<<dim3(24, 32), 256, 0, stream>>>(xc, 1024, 1, WqkvT,
                                                qkv, 3072, 0, 1024, nullptr);
      attn_blockdiag<<<dim3(64), 512, 0, stream>>>(qkv);
      gemm_bt_p<<<dim3(8, 32), 256, 0, stream>>>(qkv, 3072, Woutb,
                                                 outc, 1024, 1, 1024, bout);
    }
  }
}